// Round 13
// baseline (291.316 us; speedup 1.0000x reference)
//
#include <hip/hip_runtime.h>
#include <hip/hip_fp16.h>

#define N_NODES 100000
#define N_EDGES 3200000
#define F_IN 256
#define H1 64
#define H2C 32
#define NCLS 2
#define EPS 1e-5f

#define NBK 391            // ceil(100000/256) buckets of 256 dst nodes
#define BK_CAP 10240       // per-bucket capacity (mean 8184, sd ~90; >20 sigma margin)
#define SCHUNK 32768       // edges per scatter block -> 98 blocks

#define KPAD 264           // xt row stride in halves (256 + 8)
#define WPAD 40            // wtc row stride in halves (32 + 8)

typedef _Float16 f16x8 __attribute__((ext_vector_type(8)));
typedef float f32x4 __attribute__((ext_vector_type(4)));
typedef float fvec4 __attribute__((ext_vector_type(4)));   // native vec for nontemporal_load

// ---- single-pass bucket scatter: packed[b*BK_CAP + cursor] = (dst&255)<<24 | src ----
__global__ __launch_bounds__(256) void k_scatter1p(const int* __restrict__ src,
                                                   const int* __restrict__ dst,
                                                   int* __restrict__ cursor,
                                                   int* __restrict__ packed) {
    __shared__ int h[NBK];     // local hist, then local cursor
    __shared__ int base[NBK];  // global run base for this block
    int t = threadIdx.x;
    int e0 = blockIdx.x * SCHUNK;
    int e1 = e0 + SCHUNK; if (e1 > N_EDGES) e1 = N_EDGES;
    for (int i = t; i < NBK; i += 256) h[i] = 0;
    __syncthreads();
    for (int e = e0 + t; e < e1; e += 256)
        atomicAdd(&h[((unsigned)dst[e]) >> 8], 1);
    __syncthreads();
    for (int i = t; i < NBK; i += 256) {
        int c = h[i];
        base[i] = c ? (i * BK_CAP + atomicAdd(&cursor[i], c)) : 0;
        h[i] = 0;
    }
    __syncthreads();
    for (int e = e0 + t; e < e1; e += 256) {
        int d = dst[e];
        int b = ((unsigned)d) >> 8;
        int pos = base[b] + atomicAdd(&h[b], 1);
        packed[pos] = ((d & 255) << 24) | src[e];
    }
}

// ---- per-bucket CSR build (LDS counting sort) + offs/endx + dinv ----
__global__ __launch_bounds__(256) void k_csr_build(const int* __restrict__ packed,
                                                   const int* __restrict__ cursor,
                                                   int* __restrict__ csr,
                                                   int* __restrict__ offs_g,
                                                   int* __restrict__ endx_g,
                                                   float* __restrict__ dinv) {
    __shared__ int hist[256];
    __shared__ int offs[257];
    __shared__ int csr_l[BK_CAP];
    int t = threadIdx.x;
    int b = blockIdx.x;
    int node0 = b << 8;
    int nn = N_NODES - node0; if (nn > 256) nn = 256;
    int ebase = b * BK_CAP;
    int ecnt = cursor[b];
    if (ecnt > BK_CAP) ecnt = BK_CAP;   // never triggers; LDS safety

    hist[t] = 0;
    __syncthreads();
    for (int i = t; i < ecnt; i += 256)
        atomicAdd(&hist[((unsigned)packed[ebase + i]) >> 24], 1);
    __syncthreads();
    int d = hist[t];
    offs[t] = d;
    __syncthreads();
    for (int off = 1; off < 256; off <<= 1) {
        int x = (t >= off) ? offs[t - off] : 0;
        __syncthreads();
        offs[t] += x;
        __syncthreads();
    }
    int incl = offs[t];
    int excl = incl - d;
    __syncthreads();
    offs[t] = excl;
    if (t == 255) offs[256] = incl;
    hist[t] = 0;                      // reuse as per-node cursor
    __syncthreads();
    for (int i = t; i < ecnt; i += 256) {
        int p = packed[ebase + i];
        int ld = ((unsigned)p) >> 24;
        int pos = offs[ld] + atomicAdd(&hist[ld], 1);
        csr_l[pos] = p & 0xFFFFFF;
    }
    __syncthreads();
    for (int i = t; i < ecnt; i += 256)
        csr[ebase + i] = csr_l[i];
    if (t < nn) {
        offs_g[node0 + t] = ebase + excl;
        endx_g[node0 + t] = ebase + incl;
        dinv[node0 + t] = rsqrtf((float)d + 1.0f);
    }
}

// ---------------- GEMM1 via MFMA fp16: h1s = fp16((x @ W1) * dinv[n]) ----------------
__global__ __launch_bounds__(256) void k_gemm1m(const float* __restrict__ x,
                                                const float* __restrict__ W1,
                                                const float* __restrict__ dinv,
                                                unsigned short* __restrict__ h1s) {
    __shared__ __align__(16) unsigned short xt[64 * KPAD];   // 33.8 KB fp16 [node][k]
    __shared__ __align__(16) unsigned short wtc[64 * WPAD];  // 5.1 KB fp16 [col][kk] per chunk
    int t = threadIdx.x;
    int lane = t & 63;
    int w = t >> 6;
    int nodeBase = blockIdx.x * 64;

    #pragma unroll
    for (int i = 0; i < 16; i++) {
        int f = i * 256 + t;
        int node = f >> 6;
        int pos = f & 63;
        int gn = nodeBase + node; if (gn >= N_NODES) gn = N_NODES - 1;
        fvec4 v = __builtin_nontemporal_load((const fvec4*)(x + (size_t)gn * F_IN + pos * 4));
        ushort4 h;
        h.x = __half_as_ushort(__float2half(v.x));
        h.y = __half_as_ushort(__float2half(v.y));
        h.z = __half_as_ushort(__float2half(v.z));
        h.w = __half_as_ushort(__float2half(v.w));
        *(ushort4*)&xt[node * KPAD + pos * 4] = h;
    }
    f32x4 acc0 = {}, acc1 = {}, acc2 = {}, acc3 = {};
    __syncthreads();

    int am = lane & 15;
    int ag = lane >> 4;
    for (int kc = 0; kc < 8; kc++) {
        #pragma unroll
        for (int i = 0; i < 2; i++) {
            int f = i * 256 + t;
            int kk = f >> 4;
            int c4 = (f & 15) * 4;
            float4 v = *(const float4*)(W1 + (size_t)(kc * 32 + kk) * H1 + c4);
            wtc[(c4 + 0) * WPAD + kk] = __half_as_ushort(__float2half(v.x));
            wtc[(c4 + 1) * WPAD + kk] = __half_as_ushort(__float2half(v.y));
            wtc[(c4 + 2) * WPAD + kk] = __half_as_ushort(__float2half(v.z));
            wtc[(c4 + 3) * WPAD + kk] = __half_as_ushort(__float2half(v.w));
        }
        __syncthreads();
        f16x8 a = *(const f16x8*)&xt[(w * 16 + am) * KPAD + kc * 32 + ag * 8];
        f16x8 b0 = *(const f16x8*)&wtc[(0 * 16 + am) * WPAD + ag * 8];
        f16x8 b1 = *(const f16x8*)&wtc[(1 * 16 + am) * WPAD + ag * 8];
        f16x8 b2 = *(const f16x8*)&wtc[(2 * 16 + am) * WPAD + ag * 8];
        f16x8 b3 = *(const f16x8*)&wtc[(3 * 16 + am) * WPAD + ag * 8];
        acc0 = __builtin_amdgcn_mfma_f32_16x16x32_f16(a, b0, acc0, 0, 0, 0);
        acc1 = __builtin_amdgcn_mfma_f32_16x16x32_f16(a, b1, acc1, 0, 0, 0);
        acc2 = __builtin_amdgcn_mfma_f32_16x16x32_f16(a, b2, acc2, 0, 0, 0);
        acc3 = __builtin_amdgcn_mfma_f32_16x16x32_f16(a, b3, acc3, 0, 0, 0);
        __syncthreads();
    }

    #pragma unroll
    for (int r = 0; r < 4; r++) {
        int node = nodeBase + w * 16 + ag * 4 + r;
        if (node < N_NODES) {
            float dn = dinv[node];
            unsigned short* orow = &h1s[(size_t)node * H1];
            orow[ 0 + am] = __half_as_ushort(__float2half(acc0[r] * dn));
            orow[16 + am] = __half_as_ushort(__float2half(acc1[r] * dn));
            orow[32 + am] = __half_as_ushort(__float2half(acc2[r] * dn));
            orow[48 + am] = __half_as_ushort(__float2half(acc3[r] * dn));
        }
    }
}

// ---- fused agg1 + BN1 + ReLU + GEMM2 + dinv-scale: 32 lanes/node, 2 ch/lane, 16-unroll ----
__global__ __launch_bounds__(256) void k_agg1f(const unsigned short* __restrict__ h1s,
                                               const float* __restrict__ dinv,
                                               const int* __restrict__ offs,
                                               const int* __restrict__ endx,
                                               const int* __restrict__ csr,
                                               const float* __restrict__ b1,
                                               const float* __restrict__ g1,
                                               const float* __restrict__ be1,
                                               const float* __restrict__ m1,
                                               const float* __restrict__ v1,
                                               const float* __restrict__ W2,
                                               unsigned short* __restrict__ h2s) {
    __shared__ float w2[H1 * H2C];   // natural layout [c][j]
    __shared__ float rows[8][64];
    int t = threadIdx.x;
    for (int i = t; i < H1 * H2C; i += 256) w2[i] = W2[i];
    __syncthreads();

    int slot = t >> 5;
    int cp = t & 31;
    int n = blockIdx.x * 8 + slot;
    const ushort2* hp = (const ushort2*)h1s;   // [N][32]
    float sx = 0.f, sy = 0.f;
    int k = offs[n], kend = endx[n];
    for (; k + 15 < kend; k += 16) {
        int s0 = csr[k],      s1 = csr[k + 1],  s2 = csr[k + 2],  s3 = csr[k + 3];
        int s4 = csr[k + 4],  s5 = csr[k + 5],  s6 = csr[k + 6],  s7 = csr[k + 7];
        int s8 = csr[k + 8],  s9 = csr[k + 9],  sa = csr[k + 10], sb = csr[k + 11];
        int sc = csr[k + 12], sd = csr[k + 13], se = csr[k + 14], sf = csr[k + 15];
        ushort2 u0 = hp[(size_t)s0 * 32 + cp], u1 = hp[(size_t)s1 * 32 + cp];
        ushort2 u2 = hp[(size_t)s2 * 32 + cp], u3 = hp[(size_t)s3 * 32 + cp];
        ushort2 u4 = hp[(size_t)s4 * 32 + cp], u5 = hp[(size_t)s5 * 32 + cp];
        ushort2 u6 = hp[(size_t)s6 * 32 + cp], u7 = hp[(size_t)s7 * 32 + cp];
        ushort2 u8 = hp[(size_t)s8 * 32 + cp], u9 = hp[(size_t)s9 * 32 + cp];
        ushort2 ua = hp[(size_t)sa * 32 + cp], ub = hp[(size_t)sb * 32 + cp];
        ushort2 uc = hp[(size_t)sc * 32 + cp], ud = hp[(size_t)sd * 32 + cp];
        ushort2 ue = hp[(size_t)se * 32 + cp], uf = hp[(size_t)sf * 32 + cp];
        float2 f0 = __half22float2(*(const __half2*)&u0);
        float2 f1 = __half22float2(*(const __half2*)&u1);
        float2 f2 = __half22float2(*(const __half2*)&u2);
        float2 f3 = __half22float2(*(const __half2*)&u3);
        float2 f4 = __half22float2(*(const __half2*)&u4);
        float2 f5 = __half22float2(*(const __half2*)&u5);
        float2 f6 = __half22float2(*(const __half2*)&u6);
        float2 f7 = __half22float2(*(const __half2*)&u7);
        float2 f8 = __half22float2(*(const __half2*)&u8);
        float2 f9 = __half22float2(*(const __half2*)&u9);
        float2 fa = __half22float2(*(const __half2*)&ua);
        float2 fb = __half22float2(*(const __half2*)&ub);
        float2 fc = __half22float2(*(const __half2*)&uc);
        float2 fd = __half22float2(*(const __half2*)&ud);
        float2 fe = __half22float2(*(const __half2*)&ue);
        float2 ff = __half22float2(*(const __half2*)&uf);
        sx += ((f0.x + f1.x) + (f2.x + f3.x)) + ((f4.x + f5.x) + (f6.x + f7.x))
            + ((f8.x + f9.x) + (fa.x + fb.x)) + ((fc.x + fd.x) + (fe.x + ff.x));
        sy += ((f0.y + f1.y) + (f2.y + f3.y)) + ((f4.y + f5.y) + (f6.y + f7.y))
            + ((f8.y + f9.y) + (fa.y + fb.y)) + ((fc.y + fd.y) + (fe.y + ff.y));
    }
    for (; k + 7 < kend; k += 8) {
        int s0 = csr[k],     s1 = csr[k + 1], s2 = csr[k + 2], s3 = csr[k + 3];
        int s4 = csr[k + 4], s5 = csr[k + 5], s6 = csr[k + 6], s7 = csr[k + 7];
        ushort2 u0 = hp[(size_t)s0 * 32 + cp], u1 = hp[(size_t)s1 * 32 + cp];
        ushort2 u2 = hp[(size_t)s2 * 32 + cp], u3 = hp[(size_t)s3 * 32 + cp];
        ushort2 u4 = hp[(size_t)s4 * 32 + cp], u5 = hp[(size_t)s5 * 32 + cp];
        ushort2 u6 = hp[(size_t)s6 * 32 + cp], u7 = hp[(size_t)s7 * 32 + cp];
        float2 f0 = __half22float2(*(const __half2*)&u0);
        float2 f1 = __half22float2(*(const __half2*)&u1);
        float2 f2 = __half22float2(*(const __half2*)&u2);
        float2 f3 = __half22float2(*(const __half2*)&u3);
        float2 f4 = __half22float2(*(const __half2*)&u4);
        float2 f5 = __half22float2(*(const __half2*)&u5);
        float2 f6 = __half22float2(*(const __half2*)&u6);
        float2 f7 = __half22float2(*(const __half2*)&u7);
        sx += (f0.x + f1.x) + (f2.x + f3.x) + ((f4.x + f5.x) + (f6.x + f7.x));
        sy += (f0.y + f1.y) + (f2.y + f3.y) + ((f4.y + f5.y) + (f6.y + f7.y));
    }
    if (k < kend) {
        int last = kend - 1;
        int i1 = k + 1 <= last ? k + 1 : last;
        int i2 = k + 2 <= last ? k + 2 : last;
        int i3 = k + 3 <= last ? k + 3 : last;
        int i4 = k + 4 <= last ? k + 4 : last;
        int i5 = k + 5 <= last ? k + 5 : last;
        int i6 = k + 6 <= last ? k + 6 : last;
        int s0 = csr[k],  s1 = csr[i1], s2 = csr[i2], s3 = csr[i3];
        int s4 = csr[i4], s5 = csr[i5], s6 = csr[i6];
        ushort2 u0 = hp[(size_t)s0 * 32 + cp], u1 = hp[(size_t)s1 * 32 + cp];
        ushort2 u2 = hp[(size_t)s2 * 32 + cp], u3 = hp[(size_t)s3 * 32 + cp];
        ushort2 u4 = hp[(size_t)s4 * 32 + cp], u5 = hp[(size_t)s5 * 32 + cp];
        ushort2 u6 = hp[(size_t)s6 * 32 + cp];
        float2 f0 = __half22float2(*(const __half2*)&u0);
        float2 f1 = __half22float2(*(const __half2*)&u1);
        float2 f2 = __half22float2(*(const __half2*)&u2);
        float2 f3 = __half22float2(*(const __half2*)&u3);
        float2 f4 = __half22float2(*(const __half2*)&u4);
        float2 f5 = __half22float2(*(const __half2*)&u5);
        float2 f6 = __half22float2(*(const __half2*)&u6);
        float m1v = (k + 1 <= last) ? 1.f : 0.f;
        float m2v = (k + 2 <= last) ? 1.f : 0.f;
        float m3v = (k + 3 <= last) ? 1.f : 0.f;
        float m4v = (k + 4 <= last) ? 1.f : 0.f;
        float m5v = (k + 5 <= last) ? 1.f : 0.f;
        float m6v = (k + 6 <= last) ? 1.f : 0.f;
        sx += f0.x + m1v * f1.x + m2v * f2.x + m3v * f3.x + m4v * f4.x + m5v * f5.x + m6v * f6.x;
        sy += f0.y + m1v * f1.y + m2v * f2.y + m3v * f3.y + m4v * f4.y + m5v * f5.y + m6v * f6.y;
    }
    // self term (pre-scaled by dinv[n]) + BN1 + ReLU
    ushort2 su = hp[(size_t)n * 32 + cp];
    float2 sf2 = __half22float2(*(const __half2*)&su);
    float dn = dinv[n];
    int c0 = cp * 2, c1 = c0 + 1;
    float r0 = (sx + sf2.x) * dn + b1[c0];
    float r1 = (sy + sf2.y) * dn + b1[c1];
    r0 = (r0 - m1[c0]) * rsqrtf(v1[c0] + EPS) * g1[c0] + be1[c0];
    r1 = (r1 - m1[c1]) * rsqrtf(v1[c1] + EPS) * g1[c1] + be1[c1];
    rows[slot][c0] = fmaxf(r0, 0.f);
    rows[slot][c1] = fmaxf(r1, 0.f);
    __builtin_amdgcn_wave_barrier();   // same-wave LDS RAW
    const float4* rp = (const float4*)rows[slot];
    float acc = 0.f;
    #pragma unroll
    for (int q = 0; q < 16; q++) {
        float4 rv = rp[q];
        int kb = q * 4;
        acc += rv.x * w2[(kb + 0) * H2C + cp] + rv.y * w2[(kb + 1) * H2C + cp]
             + rv.z * w2[(kb + 2) * H2C + cp] + rv.w * w2[(kb + 3) * H2C + cp];
    }
    h2s[(size_t)n * H2C + cp] = __half_as_ushort(__float2half(acc * dn));
}

// ---------------- agg2 + BN2 + ReLU + linear: 16 lanes/node, 2 ch/lane, 16-unroll ----------------
__global__ __launch_bounds__(256) void k_agg2(const unsigned short* __restrict__ h2s,
                                              const float* __restrict__ dinv,
                                              const int* __restrict__ offs,
                                              const int* __restrict__ endx,
                                              const int* __restrict__ csr,
                                              const float* __restrict__ b2,
                                              const float* __restrict__ g2,
                                              const float* __restrict__ be2,
                                              const float* __restrict__ m2,
                                              const float* __restrict__ v2,
                                              const float* __restrict__ Wl,
                                              const float* __restrict__ bl,
                                              float* __restrict__ out) {
    int gid = blockIdx.x * 256 + threadIdx.x;
    int n = gid >> 4;
    int cp = gid & 15;
    if (n >= N_NODES) return;
    const ushort2* hp = (const ushort2*)h2s;   // [N][16]
    float sx = 0.f, sy = 0.f;
    int k = offs[n], kend = endx[n];
    for (; k + 15 < kend; k += 16) {
        int s0 = csr[k],      s1 = csr[k + 1],  s2 = csr[k + 2],  s3 = csr[k + 3];
        int s4 = csr[k + 4],  s5 = csr[k + 5],  s6 = csr[k + 6],  s7 = csr[k + 7];
        int s8 = csr[k + 8],  s9 = csr[k + 9],  sa = csr[k + 10], sb = csr[k + 11];
        int sc = csr[k + 12], sd = csr[k + 13], se = csr[k + 14], sf = csr[k + 15];
        ushort2 u0 = hp[(size_t)s0 * 16 + cp], u1 = hp[(size_t)s1 * 16 + cp];
        ushort2 u2 = hp[(size_t)s2 * 16 + cp], u3 = hp[(size_t)s3 * 16 + cp];
        ushort2 u4 = hp[(size_t)s4 * 16 + cp], u5 = hp[(size_t)s5 * 16 + cp];
        ushort2 u6 = hp[(size_t)s6 * 16 + cp], u7 = hp[(size_t)s7 * 16 + cp];
        ushort2 u8 = hp[(size_t)s8 * 16 + cp], u9 = hp[(size_t)s9 * 16 + cp];
        ushort2 ua = hp[(size_t)sa * 16 + cp], ub = hp[(size_t)sb * 16 + cp];
        ushort2 uc = hp[(size_t)sc * 16 + cp], ud = hp[(size_t)sd * 16 + cp];
        ushort2 ue = hp[(size_t)se * 16 + cp], uf = hp[(size_t)sf * 16 + cp];
        float2 f0 = __half22float2(*(const __half2*)&u0);
        float2 f1 = __half22float2(*(const __half2*)&u1);
        float2 f2 = __half22float2(*(const __half2*)&u2);
        float2 f3 = __half22float2(*(const __half2*)&u3);
        float2 f4 = __half22float2(*(const __half2*)&u4);
        float2 f5 = __half22float2(*(const __half2*)&u5);
        float2 f6 = __half22float2(*(const __half2*)&u6);
        float2 f7 = __half22float2(*(const __half2*)&u7);
        float2 f8 = __half22float2(*(const __half2*)&u8);
        float2 f9 = __half22float2(*(const __half2*)&u9);
        float2 fa = __half22float2(*(const __half2*)&ua);
        float2 fb = __half22float2(*(const __half2*)&ub);
        float2 fc = __half22float2(*(const __half2*)&uc);
        float2 fd = __half22float2(*(const __half2*)&ud);
        float2 fe = __half22float2(*(const __half2*)&ue);
        float2 ff = __half22float2(*(const __half2*)&uf);
        sx += ((f0.x + f1.x) + (f2.x + f3.x)) + ((f4.x + f5.x) + (f6.x + f7.x))
            + ((f8.x + f9.x) + (fa.x + fb.x)) + ((fc.x + fd.x) + (fe.x + ff.x));
        sy += ((f0.y + f1.y) + (f2.y + f3.y)) + ((f4.y + f5.y) + (f6.y + f7.y))
            + ((f8.y + f9.y) + (fa.y + fb.y)) + ((fc.y + fd.y) + (fe.y + ff.y));
    }
    for (; k + 7 < kend; k += 8) {
        int s0 = csr[k],     s1 = csr[k + 1], s2 = csr[k + 2], s3 = csr[k + 3];
        int s4 = csr[k + 4], s5 = csr[k + 5], s6 = csr[k + 6], s7 = csr[k + 7];
        ushort2 u0 = hp[(size_t)s0 * 16 + cp], u1 = hp[(size_t)s1 * 16 + cp];
        ushort2 u2 = hp[(size_t)s2 * 16 + cp], u3 = hp[(size_t)s3 * 16 + cp];
        ushort2 u4 = hp[(size_t)s4 * 16 + cp], u5 = hp[(size_t)s5 * 16 + cp];
        ushort2 u6 = hp[(size_t)s6 * 16 + cp], u7 = hp[(size_t)s7 * 16 + cp];
        float2 f0 = __half22float2(*(const __half2*)&u0);
        float2 f1 = __half22float2(*(const __half2*)&u1);
        float2 f2 = __half22float2(*(const __half2*)&u2);
        float2 f3 = __half22float2(*(const __half2*)&u3);
        float2 f4 = __half22float2(*(const __half2*)&u4);
        float2 f5 = __half22float2(*(const __half2*)&u5);
        float2 f6 = __half22float2(*(const __half2*)&u6);
        float2 f7 = __half22float2(*(const __half2*)&u7);
        sx += (f0.x + f1.x) + (f2.x + f3.x) + ((f4.x + f5.x) + (f6.x + f7.x));
        sy += (f0.y + f1.y) + (f2.y + f3.y) + ((f4.y + f5.y) + (f6.y + f7.y));
    }
    if (k < kend) {
        int last = kend - 1;
        int i1 = k + 1 <= last ? k + 1 : last;
        int i2 = k + 2 <= last ? k + 2 : last;
        int i3 = k + 3 <= last ? k + 3 : last;
        int i4 = k + 4 <= last ? k + 4 : last;
        int i5 = k + 5 <= last ? k + 5 : last;
        int i6 = k + 6 <= last ? k + 6 : last;
        int s0 = csr[k],  s1 = csr[i1], s2 = csr[i2], s3 = csr[i3];
        int s4 = csr[i4], s5 = csr[i5], s6 = csr[i6];
        ushort2 u0 = hp[(size_t)s0 * 16 + cp], u1 = hp[(size_t)s1 * 16 + cp];
        ushort2 u2 = hp[(size_t)s2 * 16 + cp], u3 = hp[(size_t)s3 * 16 + cp];
        ushort2 u4 = hp[(size_t)s4 * 16 + cp], u5 = hp[(size_t)s5 * 16 + cp];
        ushort2 u6 = hp[(size_t)s6 * 16 + cp];
        float2 f0 = __half22float2(*(const __half2*)&u0);
        float2 f1 = __half22float2(*(const __half2*)&u1);
        float2 f2 = __half22float2(*(const __half2*)&u2);
        float2 f3 = __half22float2(*(const __half2*)&u3);
        float2 f4 = __half22float2(*(const __half2*)&u4);
        float2 f5 = __half22float2(*(const __half2*)&u5);
        float2 f6 = __half22float2(*(const __half2*)&u6);
        float m1v = (k + 1 <= last) ? 1.f : 0.f;
        float m2v = (k + 2 <= last) ? 1.f : 0.f;
        float m3v = (k + 3 <= last) ? 1.f : 0.f;
        float m4v = (k + 4 <= last) ? 1.f : 0.f;
        float m5v = (k + 5 <= last) ? 1.f : 0.f;
        float m6v = (k + 6 <= last) ? 1.f : 0.f;
        sx += f0.x + m1v * f1.x + m2v * f2.x + m3v * f3.x + m4v * f4.x + m5v * f5.x + m6v * f6.x;
        sy += f0.y + m1v * f1.y + m2v * f2.y + m3v * f3.y + m4v * f4.y + m5v * f5.y + m6v * f6.y;
    }
    ushort2 su = hp[(size_t)n * 16 + cp];
    float2 sf2 = __half22float2(*(const __half2*)&su);
    float dn = dinv[n];
    int c0 = cp * 2, c1 = c0 + 1;
    float r0 = (sx + sf2.x) * dn + b2[c0];
    float r1 = (sy + sf2.y) * dn + b2[c1];
    r0 = (r0 - m2[c0]) * rsqrtf(v2[c0] + EPS) * g2[c0] + be2[c0];
    r1 = (r1 - m2[c1]) * rsqrtf(v2[c1] + EPS) * g2[c1] + be2[c1];
    r0 = fmaxf(r0, 0.f);
    r1 = fmaxf(r1, 0.f);
    float p0 = r0 * Wl[c0 * 2 + 0] + r1 * Wl[c1 * 2 + 0];
    float p1 = r0 * Wl[c0 * 2 + 1] + r1 * Wl[c1 * 2 + 1];
    #pragma unroll
    for (int off = 8; off > 0; off >>= 1) {
        p0 += __shfl_xor(p0, off);
        p1 += __shfl_xor(p1, off);
    }
    if (cp == 0) {
        *(float2*)&out[(size_t)n * NCLS] = make_float2(p0 + bl[0], p1 + bl[1]);
    }
}

extern "C" void kernel_launch(void* const* d_in, const int* in_sizes, int n_in,
                              void* d_out, int out_size, void* d_ws, size_t ws_size,
                              hipStream_t stream) {
    const float* x   = (const float*)d_in[0];
    const int*   ei  = (const int*)d_in[1];
    const int*   src = ei;
    const int*   dst = ei + N_EDGES;
    const float* W1  = (const float*)d_in[2];
    const float* b1  = (const float*)d_in[3];
    const float* g1  = (const float*)d_in[4];
    const float* be1 = (const float*)d_in[5];
    const float* m1  = (const float*)d_in[6];
    const float* v1  = (const float*)d_in[7];
    const float* W2  = (const float*)d_in[8];
    const float* b2  = (const float*)d_in[9];
    const float* g2  = (const float*)d_in[10];
    const float* be2 = (const float*)d_in[11];
    const float* m2  = (const float*)d_in[12];
    const float* v2  = (const float*)d_in[13];
    const float* Wl  = (const float*)d_in[14];
    const float* bl  = (const float*)d_in[15];
    float* out = (float*)d_out;

    char* p = (char*)d_ws;
    int*   cursor  = (int*)p;  p += 1600;                          // NBK ints (+pad)
    int*   offs    = (int*)p;  p += 400000;                        // N ints (start)
    int*   endx    = (int*)p;  p += 400000;                        // N ints (end)
    float* dinv    = (float*)p; p += 400000;                       // N floats
    int*   packed  = (int*)p;  p += (size_t)NBK * BK_CAP * 4;      // bucket-strided records
    int*   csr     = (int*)p;  p += (size_t)NBK * BK_CAP * 4;      // bucket-strided csr
    unsigned short* h1s = (unsigned short*)p; p += (size_t)N_NODES * H1 * 2;   // fp16 [N][64], dinv-scaled
    unsigned short* h2s = (unsigned short*)p; p += (size_t)N_NODES * H2C * 2;  // fp16 [N][32], dinv-scaled

    (void)hipMemsetAsync(cursor, 0, 1600, stream);

    k_scatter1p<<<(N_EDGES + SCHUNK - 1) / SCHUNK, 256, 0, stream>>>(src, dst, cursor, packed);
    k_csr_build<<<NBK, 256, 0, stream>>>(packed, cursor, csr, offs, endx, dinv);
    k_gemm1m<<<(N_NODES + 63) / 64, 256, 0, stream>>>(x, W1, dinv, h1s);
    k_agg1f<<<N_NODES / 8, 256, 0, stream>>>(h1s, dinv, offs, endx, csr, b1, g1, be1, m1, v1, W2, h2s);
    k_agg2<<<(N_NODES * 16) / 256, 256, 0, stream>>>(h2s, dinv, offs, endx, csr, b2, g2, be2, m2, v2, Wl, bl, out);
}

// Round 14
// 225.997 us; speedup vs baseline: 1.2890x; 1.2890x over previous
//
#include <hip/hip_runtime.h>
#include <hip/hip_fp16.h>

#define N_NODES 100000
#define N_EDGES 3200000
#define F_IN 256
#define H1 64
#define H2C 32
#define NCLS 2
#define EPS 1e-5f

#define NBK 391            // ceil(100000/256) buckets of 256 dst nodes
#define BK_CAP 10240       // per-bucket capacity (mean 8184, sd ~90; >20 sigma margin)
#define SCHUNK 8192        // edges per scatter block -> 391 blocks (all CUs busy)

#define KPAD 264           // xt row stride in halves (256 + 8)
#define WPAD 40            // wtc row stride in halves (32 + 8)

typedef _Float16 f16x8 __attribute__((ext_vector_type(8)));
typedef float f32x4 __attribute__((ext_vector_type(4)));
typedef float fvec4 __attribute__((ext_vector_type(4)));   // native vec for nontemporal_load

// ---- single-pass bucket scatter: packed[b*BK_CAP + cursor] = (dst&255)<<24 | src ----
__global__ __launch_bounds__(256) void k_scatter1p(const int* __restrict__ src,
                                                   const int* __restrict__ dst,
                                                   int* __restrict__ cursor,
                                                   int* __restrict__ packed) {
    __shared__ int h[NBK];     // local hist, then local cursor
    __shared__ int base[NBK];  // global run base for this block
    int t = threadIdx.x;
    int e0 = blockIdx.x * SCHUNK;
    int e1 = e0 + SCHUNK; if (e1 > N_EDGES) e1 = N_EDGES;
    for (int i = t; i < NBK; i += 256) h[i] = 0;
    __syncthreads();
    for (int e = e0 + t; e < e1; e += 256)
        atomicAdd(&h[((unsigned)dst[e]) >> 8], 1);
    __syncthreads();
    for (int i = t; i < NBK; i += 256) {
        int c = h[i];
        base[i] = c ? (i * BK_CAP + atomicAdd(&cursor[i], c)) : 0;
        h[i] = 0;
    }
    __syncthreads();
    for (int e = e0 + t; e < e1; e += 256) {
        int d = dst[e];
        int b = ((unsigned)d) >> 8;
        int pos = base[b] + atomicAdd(&h[b], 1);
        packed[pos] = ((d & 255) << 24) | src[e];
    }
}

// ---- per-bucket CSR build (LDS counting sort) + offs/endx + dinv ----
__global__ __launch_bounds__(256) void k_csr_build(const int* __restrict__ packed,
                                                   const int* __restrict__ cursor,
                                                   int* __restrict__ csr,
                                                   int* __restrict__ offs_g,
                                                   int* __restrict__ endx_g,
                                                   float* __restrict__ dinv) {
    __shared__ int hist[256];
    __shared__ int offs[257];
    __shared__ int csr_l[BK_CAP];
    int t = threadIdx.x;
    int b = blockIdx.x;
    int node0 = b << 8;
    int nn = N_NODES - node0; if (nn > 256) nn = 256;
    int ebase = b * BK_CAP;
    int ecnt = cursor[b];
    if (ecnt > BK_CAP) ecnt = BK_CAP;   // never triggers; LDS safety

    hist[t] = 0;
    __syncthreads();
    for (int i = t; i < ecnt; i += 256)
        atomicAdd(&hist[((unsigned)packed[ebase + i]) >> 24], 1);
    __syncthreads();
    int d = hist[t];
    offs[t] = d;
    __syncthreads();
    for (int off = 1; off < 256; off <<= 1) {
        int x = (t >= off) ? offs[t - off] : 0;
        __syncthreads();
        offs[t] += x;
        __syncthreads();
    }
    int incl = offs[t];
    int excl = incl - d;
    __syncthreads();
    offs[t] = excl;
    if (t == 255) offs[256] = incl;
    hist[t] = 0;                      // reuse as per-node cursor
    __syncthreads();
    for (int i = t; i < ecnt; i += 256) {
        int p = packed[ebase + i];
        int ld = ((unsigned)p) >> 24;
        int pos = offs[ld] + atomicAdd(&hist[ld], 1);
        csr_l[pos] = p & 0xFFFFFF;
    }
    __syncthreads();
    for (int i = t; i < ecnt; i += 256)
        csr[ebase + i] = csr_l[i];
    if (t < nn) {
        offs_g[node0 + t] = ebase + excl;
        endx_g[node0 + t] = ebase + incl;
        dinv[node0 + t] = rsqrtf((float)d + 1.0f);
    }
}

// ---------------- GEMM1 via MFMA fp16: h1s = fp16((x @ W1) * dinv[n]) ----------------
__global__ __launch_bounds__(256) void k_gemm1m(const float* __restrict__ x,
                                                const float* __restrict__ W1,
                                                const float* __restrict__ dinv,
                                                unsigned short* __restrict__ h1s) {
    __shared__ __align__(16) unsigned short xt[64 * KPAD];   // 33.8 KB fp16 [node][k]
    __shared__ __align__(16) unsigned short wtc[64 * WPAD];  // 5.1 KB fp16 [col][kk] per chunk
    int t = threadIdx.x;
    int lane = t & 63;
    int w = t >> 6;
    int nodeBase = blockIdx.x * 64;

    #pragma unroll
    for (int i = 0; i < 16; i++) {
        int f = i * 256 + t;
        int node = f >> 6;
        int pos = f & 63;
        int gn = nodeBase + node; if (gn >= N_NODES) gn = N_NODES - 1;
        fvec4 v = __builtin_nontemporal_load((const fvec4*)(x + (size_t)gn * F_IN + pos * 4));
        ushort4 h;
        h.x = __half_as_ushort(__float2half(v.x));
        h.y = __half_as_ushort(__float2half(v.y));
        h.z = __half_as_ushort(__float2half(v.z));
        h.w = __half_as_ushort(__float2half(v.w));
        *(ushort4*)&xt[node * KPAD + pos * 4] = h;
    }
    f32x4 acc0 = {}, acc1 = {}, acc2 = {}, acc3 = {};
    __syncthreads();

    int am = lane & 15;
    int ag = lane >> 4;
    for (int kc = 0; kc < 8; kc++) {
        #pragma unroll
        for (int i = 0; i < 2; i++) {
            int f = i * 256 + t;
            int kk = f >> 4;
            int c4 = (f & 15) * 4;
            float4 v = *(const float4*)(W1 + (size_t)(kc * 32 + kk) * H1 + c4);
            wtc[(c4 + 0) * WPAD + kk] = __half_as_ushort(__float2half(v.x));
            wtc[(c4 + 1) * WPAD + kk] = __half_as_ushort(__float2half(v.y));
            wtc[(c4 + 2) * WPAD + kk] = __half_as_ushort(__float2half(v.z));
            wtc[(c4 + 3) * WPAD + kk] = __half_as_ushort(__float2half(v.w));
        }
        __syncthreads();
        f16x8 a = *(const f16x8*)&xt[(w * 16 + am) * KPAD + kc * 32 + ag * 8];
        f16x8 b0 = *(const f16x8*)&wtc[(0 * 16 + am) * WPAD + ag * 8];
        f16x8 b1 = *(const f16x8*)&wtc[(1 * 16 + am) * WPAD + ag * 8];
        f16x8 b2 = *(const f16x8*)&wtc[(2 * 16 + am) * WPAD + ag * 8];
        f16x8 b3 = *(const f16x8*)&wtc[(3 * 16 + am) * WPAD + ag * 8];
        acc0 = __builtin_amdgcn_mfma_f32_16x16x32_f16(a, b0, acc0, 0, 0, 0);
        acc1 = __builtin_amdgcn_mfma_f32_16x16x32_f16(a, b1, acc1, 0, 0, 0);
        acc2 = __builtin_amdgcn_mfma_f32_16x16x32_f16(a, b2, acc2, 0, 0, 0);
        acc3 = __builtin_amdgcn_mfma_f32_16x16x32_f16(a, b3, acc3, 0, 0, 0);
        __syncthreads();
    }

    #pragma unroll
    for (int r = 0; r < 4; r++) {
        int node = nodeBase + w * 16 + ag * 4 + r;
        if (node < N_NODES) {
            float dn = dinv[node];
            unsigned short* orow = &h1s[(size_t)node * H1];
            orow[ 0 + am] = __half_as_ushort(__float2half(acc0[r] * dn));
            orow[16 + am] = __half_as_ushort(__float2half(acc1[r] * dn));
            orow[32 + am] = __half_as_ushort(__float2half(acc2[r] * dn));
            orow[48 + am] = __half_as_ushort(__float2half(acc3[r] * dn));
        }
    }
}

// ---- fused agg1 + BN1 + ReLU + GEMM2 + dinv-scale: 32 lanes/node, 2 ch/lane, 16-unroll ----
__global__ __launch_bounds__(256) void k_agg1f(const unsigned short* __restrict__ h1s,
                                               const float* __restrict__ dinv,
                                               const int* __restrict__ offs,
                                               const int* __restrict__ endx,
                                               const int* __restrict__ csr,
                                               const float* __restrict__ b1,
                                               const float* __restrict__ g1,
                                               const float* __restrict__ be1,
                                               const float* __restrict__ m1,
                                               const float* __restrict__ v1,
                                               const float* __restrict__ W2,
                                               unsigned short* __restrict__ h2s) {
    __shared__ float w2[H1 * H2C];   // natural layout [c][j]
    __shared__ float rows[8][64];
    int t = threadIdx.x;
    for (int i = t; i < H1 * H2C; i += 256) w2[i] = W2[i];
    __syncthreads();

    int slot = t >> 5;
    int cp = t & 31;
    int n = blockIdx.x * 8 + slot;
    const ushort2* hp = (const ushort2*)h1s;   // [N][32]
    float sx = 0.f, sy = 0.f;
    int k = offs[n], kend = endx[n];
    for (; k + 15 < kend; k += 16) {
        int s0 = csr[k],      s1 = csr[k + 1],  s2 = csr[k + 2],  s3 = csr[k + 3];
        int s4 = csr[k + 4],  s5 = csr[k + 5],  s6 = csr[k + 6],  s7 = csr[k + 7];
        int s8 = csr[k + 8],  s9 = csr[k + 9],  sa = csr[k + 10], sb = csr[k + 11];
        int sc = csr[k + 12], sd = csr[k + 13], se = csr[k + 14], sf = csr[k + 15];
        ushort2 u0 = hp[(size_t)s0 * 32 + cp], u1 = hp[(size_t)s1 * 32 + cp];
        ushort2 u2 = hp[(size_t)s2 * 32 + cp], u3 = hp[(size_t)s3 * 32 + cp];
        ushort2 u4 = hp[(size_t)s4 * 32 + cp], u5 = hp[(size_t)s5 * 32 + cp];
        ushort2 u6 = hp[(size_t)s6 * 32 + cp], u7 = hp[(size_t)s7 * 32 + cp];
        ushort2 u8 = hp[(size_t)s8 * 32 + cp], u9 = hp[(size_t)s9 * 32 + cp];
        ushort2 ua = hp[(size_t)sa * 32 + cp], ub = hp[(size_t)sb * 32 + cp];
        ushort2 uc = hp[(size_t)sc * 32 + cp], ud = hp[(size_t)sd * 32 + cp];
        ushort2 ue = hp[(size_t)se * 32 + cp], uf = hp[(size_t)sf * 32 + cp];
        float2 f0 = __half22float2(*(const __half2*)&u0);
        float2 f1 = __half22float2(*(const __half2*)&u1);
        float2 f2 = __half22float2(*(const __half2*)&u2);
        float2 f3 = __half22float2(*(const __half2*)&u3);
        float2 f4 = __half22float2(*(const __half2*)&u4);
        float2 f5 = __half22float2(*(const __half2*)&u5);
        float2 f6 = __half22float2(*(const __half2*)&u6);
        float2 f7 = __half22float2(*(const __half2*)&u7);
        float2 f8 = __half22float2(*(const __half2*)&u8);
        float2 f9 = __half22float2(*(const __half2*)&u9);
        float2 fa = __half22float2(*(const __half2*)&ua);
        float2 fb = __half22float2(*(const __half2*)&ub);
        float2 fc = __half22float2(*(const __half2*)&uc);
        float2 fd = __half22float2(*(const __half2*)&ud);
        float2 fe = __half22float2(*(const __half2*)&ue);
        float2 ff = __half22float2(*(const __half2*)&uf);
        sx += ((f0.x + f1.x) + (f2.x + f3.x)) + ((f4.x + f5.x) + (f6.x + f7.x))
            + ((f8.x + f9.x) + (fa.x + fb.x)) + ((fc.x + fd.x) + (fe.x + ff.x));
        sy += ((f0.y + f1.y) + (f2.y + f3.y)) + ((f4.y + f5.y) + (f6.y + f7.y))
            + ((f8.y + f9.y) + (fa.y + fb.y)) + ((fc.y + fd.y) + (fe.y + ff.y));
    }
    for (; k + 7 < kend; k += 8) {
        int s0 = csr[k],     s1 = csr[k + 1], s2 = csr[k + 2], s3 = csr[k + 3];
        int s4 = csr[k + 4], s5 = csr[k + 5], s6 = csr[k + 6], s7 = csr[k + 7];
        ushort2 u0 = hp[(size_t)s0 * 32 + cp], u1 = hp[(size_t)s1 * 32 + cp];
        ushort2 u2 = hp[(size_t)s2 * 32 + cp], u3 = hp[(size_t)s3 * 32 + cp];
        ushort2 u4 = hp[(size_t)s4 * 32 + cp], u5 = hp[(size_t)s5 * 32 + cp];
        ushort2 u6 = hp[(size_t)s6 * 32 + cp], u7 = hp[(size_t)s7 * 32 + cp];
        float2 f0 = __half22float2(*(const __half2*)&u0);
        float2 f1 = __half22float2(*(const __half2*)&u1);
        float2 f2 = __half22float2(*(const __half2*)&u2);
        float2 f3 = __half22float2(*(const __half2*)&u3);
        float2 f4 = __half22float2(*(const __half2*)&u4);
        float2 f5 = __half22float2(*(const __half2*)&u5);
        float2 f6 = __half22float2(*(const __half2*)&u6);
        float2 f7 = __half22float2(*(const __half2*)&u7);
        sx += (f0.x + f1.x) + (f2.x + f3.x) + ((f4.x + f5.x) + (f6.x + f7.x));
        sy += (f0.y + f1.y) + (f2.y + f3.y) + ((f4.y + f5.y) + (f6.y + f7.y));
    }
    if (k < kend) {
        int last = kend - 1;
        int i1 = k + 1 <= last ? k + 1 : last;
        int i2 = k + 2 <= last ? k + 2 : last;
        int i3 = k + 3 <= last ? k + 3 : last;
        int i4 = k + 4 <= last ? k + 4 : last;
        int i5 = k + 5 <= last ? k + 5 : last;
        int i6 = k + 6 <= last ? k + 6 : last;
        int s0 = csr[k],  s1 = csr[i1], s2 = csr[i2], s3 = csr[i3];
        int s4 = csr[i4], s5 = csr[i5], s6 = csr[i6];
        ushort2 u0 = hp[(size_t)s0 * 32 + cp], u1 = hp[(size_t)s1 * 32 + cp];
        ushort2 u2 = hp[(size_t)s2 * 32 + cp], u3 = hp[(size_t)s3 * 32 + cp];
        ushort2 u4 = hp[(size_t)s4 * 32 + cp], u5 = hp[(size_t)s5 * 32 + cp];
        ushort2 u6 = hp[(size_t)s6 * 32 + cp];
        float2 f0 = __half22float2(*(const __half2*)&u0);
        float2 f1 = __half22float2(*(const __half2*)&u1);
        float2 f2 = __half22float2(*(const __half2*)&u2);
        float2 f3 = __half22float2(*(const __half2*)&u3);
        float2 f4 = __half22float2(*(const __half2*)&u4);
        float2 f5 = __half22float2(*(const __half2*)&u5);
        float2 f6 = __half22float2(*(const __half2*)&u6);
        float m1v = (k + 1 <= last) ? 1.f : 0.f;
        float m2v = (k + 2 <= last) ? 1.f : 0.f;
        float m3v = (k + 3 <= last) ? 1.f : 0.f;
        float m4v = (k + 4 <= last) ? 1.f : 0.f;
        float m5v = (k + 5 <= last) ? 1.f : 0.f;
        float m6v = (k + 6 <= last) ? 1.f : 0.f;
        sx += f0.x + m1v * f1.x + m2v * f2.x + m3v * f3.x + m4v * f4.x + m5v * f5.x + m6v * f6.x;
        sy += f0.y + m1v * f1.y + m2v * f2.y + m3v * f3.y + m4v * f4.y + m5v * f5.y + m6v * f6.y;
    }
    // self term (pre-scaled by dinv[n]) + BN1 + ReLU
    ushort2 su = hp[(size_t)n * 32 + cp];
    float2 sf2 = __half22float2(*(const __half2*)&su);
    float dn = dinv[n];
    int c0 = cp * 2, c1 = c0 + 1;
    float r0 = (sx + sf2.x) * dn + b1[c0];
    float r1 = (sy + sf2.y) * dn + b1[c1];
    r0 = (r0 - m1[c0]) * rsqrtf(v1[c0] + EPS) * g1[c0] + be1[c0];
    r1 = (r1 - m1[c1]) * rsqrtf(v1[c1] + EPS) * g1[c1] + be1[c1];
    rows[slot][c0] = fmaxf(r0, 0.f);
    rows[slot][c1] = fmaxf(r1, 0.f);
    __builtin_amdgcn_wave_barrier();   // same-wave LDS RAW
    const float4* rp = (const float4*)rows[slot];
    float acc = 0.f;
    #pragma unroll
    for (int q = 0; q < 16; q++) {
        float4 rv = rp[q];
        int kb = q * 4;
        acc += rv.x * w2[(kb + 0) * H2C + cp] + rv.y * w2[(kb + 1) * H2C + cp]
             + rv.z * w2[(kb + 2) * H2C + cp] + rv.w * w2[(kb + 3) * H2C + cp];
    }
    h2s[(size_t)n * H2C + cp] = __half_as_ushort(__float2half(acc * dn));
}

// ---------------- agg2 + BN2 + ReLU + linear: 16 lanes/node, 2 ch/lane, 16-unroll ----------------
__global__ __launch_bounds__(256) void k_agg2(const unsigned short* __restrict__ h2s,
                                              const float* __restrict__ dinv,
                                              const int* __restrict__ offs,
                                              const int* __restrict__ endx,
                                              const int* __restrict__ csr,
                                              const float* __restrict__ b2,
                                              const float* __restrict__ g2,
                                              const float* __restrict__ be2,
                                              const float* __restrict__ m2,
                                              const float* __restrict__ v2,
                                              const float* __restrict__ Wl,
                                              const float* __restrict__ bl,
                                              float* __restrict__ out) {
    int gid = blockIdx.x * 256 + threadIdx.x;
    int n = gid >> 4;
    int cp = gid & 15;
    if (n >= N_NODES) return;
    const ushort2* hp = (const ushort2*)h2s;   // [N][16]
    float sx = 0.f, sy = 0.f;
    int k = offs[n], kend = endx[n];
    for (; k + 15 < kend; k += 16) {
        int s0 = csr[k],      s1 = csr[k + 1],  s2 = csr[k + 2],  s3 = csr[k + 3];
        int s4 = csr[k + 4],  s5 = csr[k + 5],  s6 = csr[k + 6],  s7 = csr[k + 7];
        int s8 = csr[k + 8],  s9 = csr[k + 9],  sa = csr[k + 10], sb = csr[k + 11];
        int sc = csr[k + 12], sd = csr[k + 13], se = csr[k + 14], sf = csr[k + 15];
        ushort2 u0 = hp[(size_t)s0 * 16 + cp], u1 = hp[(size_t)s1 * 16 + cp];
        ushort2 u2 = hp[(size_t)s2 * 16 + cp], u3 = hp[(size_t)s3 * 16 + cp];
        ushort2 u4 = hp[(size_t)s4 * 16 + cp], u5 = hp[(size_t)s5 * 16 + cp];
        ushort2 u6 = hp[(size_t)s6 * 16 + cp], u7 = hp[(size_t)s7 * 16 + cp];
        ushort2 u8 = hp[(size_t)s8 * 16 + cp], u9 = hp[(size_t)s9 * 16 + cp];
        ushort2 ua = hp[(size_t)sa * 16 + cp], ub = hp[(size_t)sb * 16 + cp];
        ushort2 uc = hp[(size_t)sc * 16 + cp], ud = hp[(size_t)sd * 16 + cp];
        ushort2 ue = hp[(size_t)se * 16 + cp], uf = hp[(size_t)sf * 16 + cp];
        float2 f0 = __half22float2(*(const __half2*)&u0);
        float2 f1 = __half22float2(*(const __half2*)&u1);
        float2 f2 = __half22float2(*(const __half2*)&u2);
        float2 f3 = __half22float2(*(const __half2*)&u3);
        float2 f4 = __half22float2(*(const __half2*)&u4);
        float2 f5 = __half22float2(*(const __half2*)&u5);
        float2 f6 = __half22float2(*(const __half2*)&u6);
        float2 f7 = __half22float2(*(const __half2*)&u7);
        float2 f8 = __half22float2(*(const __half2*)&u8);
        float2 f9 = __half22float2(*(const __half2*)&u9);
        float2 fa = __half22float2(*(const __half2*)&ua);
        float2 fb = __half22float2(*(const __half2*)&ub);
        float2 fc = __half22float2(*(const __half2*)&uc);
        float2 fd = __half22float2(*(const __half2*)&ud);
        float2 fe = __half22float2(*(const __half2*)&ue);
        float2 ff = __half22float2(*(const __half2*)&uf);
        sx += ((f0.x + f1.x) + (f2.x + f3.x)) + ((f4.x + f5.x) + (f6.x + f7.x))
            + ((f8.x + f9.x) + (fa.x + fb.x)) + ((fc.x + fd.x) + (fe.x + ff.x));
        sy += ((f0.y + f1.y) + (f2.y + f3.y)) + ((f4.y + f5.y) + (f6.y + f7.y))
            + ((f8.y + f9.y) + (fa.y + fb.y)) + ((fc.y + fd.y) + (fe.y + ff.y));
    }
    for (; k + 7 < kend; k += 8) {
        int s0 = csr[k],     s1 = csr[k + 1], s2 = csr[k + 2], s3 = csr[k + 3];
        int s4 = csr[k + 4], s5 = csr[k + 5], s6 = csr[k + 6], s7 = csr[k + 7];
        ushort2 u0 = hp[(size_t)s0 * 16 + cp], u1 = hp[(size_t)s1 * 16 + cp];
        ushort2 u2 = hp[(size_t)s2 * 16 + cp], u3 = hp[(size_t)s3 * 16 + cp];
        ushort2 u4 = hp[(size_t)s4 * 16 + cp], u5 = hp[(size_t)s5 * 16 + cp];
        ushort2 u6 = hp[(size_t)s6 * 16 + cp], u7 = hp[(size_t)s7 * 16 + cp];
        float2 f0 = __half22float2(*(const __half2*)&u0);
        float2 f1 = __half22float2(*(const __half2*)&u1);
        float2 f2 = __half22float2(*(const __half2*)&u2);
        float2 f3 = __half22float2(*(const __half2*)&u3);
        float2 f4 = __half22float2(*(const __half2*)&u4);
        float2 f5 = __half22float2(*(const __half2*)&u5);
        float2 f6 = __half22float2(*(const __half2*)&u6);
        float2 f7 = __half22float2(*(const __half2*)&u7);
        sx += (f0.x + f1.x) + (f2.x + f3.x) + ((f4.x + f5.x) + (f6.x + f7.x));
        sy += (f0.y + f1.y) + (f2.y + f3.y) + ((f4.y + f5.y) + (f6.y + f7.y));
    }
    if (k < kend) {
        int last = kend - 1;
        int i1 = k + 1 <= last ? k + 1 : last;
        int i2 = k + 2 <= last ? k + 2 : last;
        int i3 = k + 3 <= last ? k + 3 : last;
        int i4 = k + 4 <= last ? k + 4 : last;
        int i5 = k + 5 <= last ? k + 5 : last;
        int i6 = k + 6 <= last ? k + 6 : last;
        int s0 = csr[k],  s1 = csr[i1], s2 = csr[i2], s3 = csr[i3];
        int s4 = csr[i4], s5 = csr[i5], s6 = csr[i6];
        ushort2 u0 = hp[(size_t)s0 * 16 + cp], u1 = hp[(size_t)s1 * 16 + cp];
        ushort2 u2 = hp[(size_t)s2 * 16 + cp], u3 = hp[(size_t)s3 * 16 + cp];
        ushort2 u4 = hp[(size_t)s4 * 16 + cp], u5 = hp[(size_t)s5 * 16 + cp];
        ushort2 u6 = hp[(size_t)s6 * 16 + cp];
        float2 f0 = __half22float2(*(const __half2*)&u0);
        float2 f1 = __half22float2(*(const __half2*)&u1);
        float2 f2 = __half22float2(*(const __half2*)&u2);
        float2 f3 = __half22float2(*(const __half2*)&u3);
        float2 f4 = __half22float2(*(const __half2*)&u4);
        float2 f5 = __half22float2(*(const __half2*)&u5);
        float2 f6 = __half22float2(*(const __half2*)&u6);
        float m1v = (k + 1 <= last) ? 1.f : 0.f;
        float m2v = (k + 2 <= last) ? 1.f : 0.f;
        float m3v = (k + 3 <= last) ? 1.f : 0.f;
        float m4v = (k + 4 <= last) ? 1.f : 0.f;
        float m5v = (k + 5 <= last) ? 1.f : 0.f;
        float m6v = (k + 6 <= last) ? 1.f : 0.f;
        sx += f0.x + m1v * f1.x + m2v * f2.x + m3v * f3.x + m4v * f4.x + m5v * f5.x + m6v * f6.x;
        sy += f0.y + m1v * f1.y + m2v * f2.y + m3v * f3.y + m4v * f4.y + m5v * f5.y + m6v * f6.y;
    }
    ushort2 su = hp[(size_t)n * 16 + cp];
    float2 sf2 = __half22float2(*(const __half2*)&su);
    float dn = dinv[n];
    int c0 = cp * 2, c1 = c0 + 1;
    float r0 = (sx + sf2.x) * dn + b2[c0];
    float r1 = (sy + sf2.y) * dn + b2[c1];
    r0 = (r0 - m2[c0]) * rsqrtf(v2[c0] + EPS) * g2[c0] + be2[c0];
    r1 = (r1 - m2[c1]) * rsqrtf(v2[c1] + EPS) * g2[c1] + be2[c1];
    r0 = fmaxf(r0, 0.f);
    r1 = fmaxf(r1, 0.f);
    float p0 = r0 * Wl[c0 * 2 + 0] + r1 * Wl[c1 * 2 + 0];
    float p1 = r0 * Wl[c0 * 2 + 1] + r1 * Wl[c1 * 2 + 1];
    #pragma unroll
    for (int off = 8; off > 0; off >>= 1) {
        p0 += __shfl_xor(p0, off);
        p1 += __shfl_xor(p1, off);
    }
    if (cp == 0) {
        *(float2*)&out[(size_t)n * NCLS] = make_float2(p0 + bl[0], p1 + bl[1]);
    }
}

extern "C" void kernel_launch(void* const* d_in, const int* in_sizes, int n_in,
                              void* d_out, int out_size, void* d_ws, size_t ws_size,
                              hipStream_t stream) {
    const float* x   = (const float*)d_in[0];
    const int*   ei  = (const int*)d_in[1];
    const int*   src = ei;
    const int*   dst = ei + N_EDGES;
    const float* W1  = (const float*)d_in[2];
    const float* b1  = (const float*)d_in[3];
    const float* g1  = (const float*)d_in[4];
    const float* be1 = (const float*)d_in[5];
    const float* m1  = (const float*)d_in[6];
    const float* v1  = (const float*)d_in[7];
    const float* W2  = (const float*)d_in[8];
    const float* b2  = (const float*)d_in[9];
    const float* g2  = (const float*)d_in[10];
    const float* be2 = (const float*)d_in[11];
    const float* m2  = (const float*)d_in[12];
    const float* v2  = (const float*)d_in[13];
    const float* Wl  = (const float*)d_in[14];
    const float* bl  = (const float*)d_in[15];
    float* out = (float*)d_out;

    char* p = (char*)d_ws;
    int*   cursor  = (int*)p;  p += 1600;                          // NBK ints (+pad)
    int*   offs    = (int*)p;  p += 400000;                        // N ints (start)
    int*   endx    = (int*)p;  p += 400000;                        // N ints (end)
    float* dinv    = (float*)p; p += 400000;                       // N floats
    int*   packed  = (int*)p;  p += (size_t)NBK * BK_CAP * 4;      // bucket-strided records
    int*   csr     = (int*)p;  p += (size_t)NBK * BK_CAP * 4;      // bucket-strided csr
    unsigned short* h1s = (unsigned short*)p; p += (size_t)N_NODES * H1 * 2;   // fp16 [N][64], dinv-scaled
    unsigned short* h2s = (unsigned short*)p; p += (size_t)N_NODES * H2C * 2;  // fp16 [N][32], dinv-scaled

    (void)hipMemsetAsync(cursor, 0, 1600, stream);

    k_scatter1p<<<(N_EDGES + SCHUNK - 1) / SCHUNK, 256, 0, stream>>>(src, dst, cursor, packed);
    k_csr_build<<<NBK, 256, 0, stream>>>(packed, cursor, csr, offs, endx, dinv);
    k_gemm1m<<<(N_NODES + 63) / 64, 256, 0, stream>>>(x, W1, dinv, h1s);
    k_agg1f<<<N_NODES / 8, 256, 0, stream>>>(h1s, dinv, offs, endx, csr, b1, g1, be1, m1, v1, W2, h2s);
    k_agg2<<<(N_NODES * 16) / 256, 256, 0, stream>>>(h2s, dinv, offs, endx, csr, b2, g2, be2, m2, v2, Wl, bl, out);
}